// Round 14
// baseline (51.867 us; speedup 1.0000x reference)
//
#include <hip/hip_runtime.h>

// AdditiveAttention: B=2,H=8,Q=512,K=512,D=64
//   scores[b,h,q,k] = V_b + sum_d V_w[d]*tanh(q_proj[q,d] + k_proj[k,d])
//
// tanh(x) = 1 - 2/(1+e^{2x});  e^{2(qp+kp)} = eq*gk,
//   eq = exp2(C*qp), gk = exp2(C*kp), C = 2*log2(e)
// term_d = Vw[d]/A_d,  A_d = 1 + eq_d*gk_d;  score = (Vb+sumVw) - 2*sum term_d
// tree8: 1 v_rcp per 8 elements (R7-proven), ~3.9 VALU/elem.
//
// KREG design (R13 post-mortem): every prior variant fetched e-values through
// a latency-serialized channel per body (LDS broadcast / s_load / readlane).
// Swap roles: lane = q; e[8] per d-group loaded ONCE from transposed LDS
// (conflict-free b32) and REUSED across the wave's 8 k; G becomes wave-uniform
// -> scalar pipe s_loads (batchable, previously idle). Output transposed via
// reused LDS for coalesced stores.

#define BHX 16
#define SEQ 512
#define DDIM 64

typedef float f4 __attribute__((ext_vector_type(4)));

// Both projections in one launch. blocks 0..255: query->eq, 256..511: keys->gk.
// (R12-proven, no pins.)
__global__ __launch_bounds__(256) void proj_kernel(
    const float* __restrict__ query, const float* __restrict__ keys,
    const float* __restrict__ Wa_w,  const float* __restrict__ Wa_b,
    const float* __restrict__ Ua_w,  const float* __restrict__ Ua_b,
    float* __restrict__ eq, float* __restrict__ gk)
{
  const int t = threadIdx.x, lane = t & 63, wave = t >> 6;
  const bool is_k = blockIdx.x >= 256;
  const float* __restrict__ X  = is_k ? keys : query;
  const float* __restrict__ W  = is_k ? Ua_w : Wa_w;
  const float* __restrict__ Bv = is_k ? Ua_b : Wa_b;
  float* __restrict__ out      = is_k ? gk : eq;
  const int row0 = (blockIdx.x & 255) * 32;

  float w[64];
  const float4* W4 = (const float4*)(W + lane * DDIM);
#pragma unroll
  for (int i = 0; i < 16; ++i) {
    float4 v = W4[i];
    w[4*i] = v.x; w[4*i+1] = v.y; w[4*i+2] = v.z; w[4*i+3] = v.w;
  }

  const float C = 2.885390081777926815f;          // 2*log2(e)
  const float b = Bv[lane];

#pragma unroll 1
  for (int i = 0; i < 8; ++i) {
    const int r   = row0 + wave * 8 + i;
    const int off = __builtin_amdgcn_readfirstlane(r * DDIM);
    const float* xr = X + off;                    // wave-uniform -> s_load
    float a0 = 0, a1 = 0, a2 = 0, a3 = 0;
#pragma unroll
    for (int e = 0; e < 64; e += 4) {
      a0 = __builtin_fmaf(xr[e],     w[e],     a0);
      a1 = __builtin_fmaf(xr[e + 1], w[e + 1], a1);
      a2 = __builtin_fmaf(xr[e + 2], w[e + 2], a2);
      a3 = __builtin_fmaf(xr[e + 3], w[e + 3], a3);
    }
    float p = ((a0 + a1) + (a2 + a3)) + b;
    out[(size_t)r * DDIM + lane] = __builtin_amdgcn_exp2f(C * p);
  }
}

// Grid (16,8,16)=2048 blocks = 8 blocks/CU. Block tile: 64 q x 32 k.
// Wave w: k in [8w, 8w+8), lane = q. LDS 16.6KB (eql, reused for out-staging).
__global__ __launch_bounds__(256, 8) void score_kernel(
    const float* __restrict__ eq,   // [BH*512][64]
    const float* __restrict__ gk,   // [BH*512][64]
    const float* __restrict__ Vw,   // [64]
    const float* __restrict__ Vb,   // [1]
    float* __restrict__ out)        // [BH,512,512]
{
  __shared__ float eql[DDIM][65];   // [d][q] transposed, +1 pad (16.6 KB)

  const int bh   = blockIdx.z;
  const int q0   = blockIdx.y * 64;
  const int k0   = blockIdx.x * 32;
  const int t    = threadIdx.x;
  const int lane = t & 63;          // = q within tile
  const int wave = t >> 6;          // k-strip

  // ---- stage eq tile TRANSPOSED: [d][q].  4 f4 reads + 16 b32 writes/thread.
  // write bank = (d+q)%32 -> 2/bank (free).
  {
    const float* eqb = eq + (size_t)(bh * SEQ + q0) * DDIM;
#pragma unroll
    for (int h = 0; h < 4; ++h) {
      const int idx = t + 256 * h;        // 0..1023 quads
      const int q   = idx >> 4;
      const int d0  = (idx & 15) * 4;
      const f4 v = *(const f4*)(eqb + q * DDIM + d0);
      eql[d0][q]     = v.x;
      eql[d0 + 1][q] = v.y;
      eql[d0 + 2][q] = v.z;
      eql[d0 + 3][q] = v.w;
    }
  }

  // acc0 = V_b + sum_d V_w[d]  (uniform scalar)
  float acc0 = Vb[0];
#pragma unroll
  for (int d = 0; d < 64; ++d) acc0 += Vw[d];

  __syncthreads();

  float acc[8] = {0.f, 0.f, 0.f, 0.f, 0.f, 0.f, 0.f, 0.f};
  // wave-uniform G base: this wave's 8 k rows
  const float* Gb = gk + (size_t)(bh * SEQ + k0 + wave * 8) * DDIM;

#pragma unroll 1
  for (int g = 0; g < 8; ++g) {           // d-groups of 8
    // lane's 8 e-values (its q-row, group g): conflict-free b32 reads,
    // loaded ONCE and reused across 8 k bodies.
    float e[8];
#pragma unroll
    for (int j = 0; j < 8; ++j) e[j] = eql[8 * g + j][lane];
    float vw[8];
#pragma unroll
    for (int j = 0; j < 8; ++j) vw[j] = Vw[8 * g + j];

#pragma unroll
    for (int kk = 0; kk < 8; ++kk) {      // wave's k-strip; acc[] static
      // wave-uniform G slice -> s_load (scalar pipe, imm offsets)
      const float* Gp = Gb + kk * DDIM + 8 * g;
      float A[8];
#pragma unroll
      for (int j = 0; j < 8; ++j)
        A[j] = __builtin_fmaf(e[j], Gp[j], 1.0f);
      // tree8: sum_j vw[j]/A[j] = num/P, 1 rcp
      const float n01 = __builtin_fmaf(vw[1], A[0], vw[0] * A[1]);
      const float n23 = __builtin_fmaf(vw[3], A[2], vw[2] * A[3]);
      const float n45 = __builtin_fmaf(vw[5], A[4], vw[4] * A[5]);
      const float n67 = __builtin_fmaf(vw[7], A[6], vw[6] * A[7]);
      const float P01 = A[0] * A[1], P23 = A[2] * A[3];
      const float P45 = A[4] * A[5], P67 = A[6] * A[7];
      const float n0123 = __builtin_fmaf(n23, P01, n01 * P23);
      const float n4567 = __builtin_fmaf(n67, P45, n45 * P67);
      const float P0123 = P01 * P23, P4567 = P45 * P67;
      const float num = __builtin_fmaf(n4567, P0123, n0123 * P4567);
      const float P   = P0123 * P4567;    // product of 8 A's >= 1: safe
      acc[kk] = __builtin_fmaf(num, __builtin_amdgcn_rcpf(P), acc[kk]);
    }
  }

  // ---- transpose results through (reused) LDS for coalesced stores ----
  __syncthreads();                        // all eql reads complete
  float* lo = &eql[0][0];                 // reuse as [64 q][33 k]
#pragma unroll
  for (int kk = 0; kk < 8; ++kk)          // bank (q + k)%32 -> 2/bank
    lo[lane * 33 + wave * 8 + kk] = __builtin_fmaf(-2.f, acc[kk], acc0);
  __syncthreads();

  {
    const int row = t >> 2;               // q row 0..63
    const int c0  = (t & 3) * 8;          // k col start
    const float* src = lo + row * 33 + c0;
    f4 v0, v1;
    v0.x = src[0]; v0.y = src[1]; v0.z = src[2]; v0.w = src[3];
    v1.x = src[4]; v1.y = src[5]; v1.z = src[6]; v1.w = src[7];
    float* dst = out + (size_t)(bh * SEQ + q0 + row) * SEQ + k0 + c0;
    *(f4*)(dst)     = v0;
    *(f4*)(dst + 4) = v1;
  }
}

extern "C" void kernel_launch(void* const* d_in, const int* in_sizes, int n_in,
                              void* d_out, int out_size, void* d_ws, size_t ws_size,
                              hipStream_t stream) {
  const float* query = (const float*)d_in[0];  // [2,8,512,64]
  const float* keys  = (const float*)d_in[1];  // [2,8,512,64]
  const float* Wa_w  = (const float*)d_in[2];  // [64,64]
  const float* Wa_b  = (const float*)d_in[3];  // [64]
  const float* Ua_w  = (const float*)d_in[4];  // [64,64]
  const float* Ua_b  = (const float*)d_in[5];  // [64]
  const float* V_w   = (const float*)d_in[6];  // [64]
  const float* V_b   = (const float*)d_in[7];  // [1]
  float* out = (float*)d_out;

  const int R = BHX * SEQ;                 // 8192 rows each side
  float* eqw = (float*)d_ws;               // 2 MiB
  float* gkw = eqw + (size_t)R * DDIM;     // 2 MiB

  proj_kernel<<<512, 256, 0, stream>>>(query, keys, Wa_w, Wa_b,
                                       Ua_w, Ua_b, eqw, gkw);

  dim3 grid(SEQ / 32, SEQ / 64, BHX);      // (16,8,16) = 2048 blocks
  score_kernel<<<grid, 256, 0, stream>>>(eqw, gkw, V_w, V_b, out);
}

// Round 15
// 40.372 us; speedup vs baseline: 1.2847x; 1.2847x over previous
//
#include <hip/hip_runtime.h>

// AdditiveAttention: B=2,H=8,Q=512,K=512,D=64
//   scores[b,h,q,k] = V_b + sum_d V_w[d]*tanh(q_proj[q,d] + k_proj[k,d])
//
// tanh(x) = 1 - 2/(1+e^{2x});  e^{2(qp+kp)} = eq*gk,
//   eq = exp2(C*qp), gk = exp2(C*kp), C = 2*log2(e)
// term_d = Vw[d]/A_d,  A_d = 1 + eq_d*gk_d;  score = (Vb+sumVw) - 2*sum term_d
// tree8: 1 v_rcp per 8 elements, ~3.75 VALU/elem.
//
// PIPE-SPLIT design (R14 post-mortem): the R12-family was bound by the
// per-CU LDS data pipe (2 broadcast b128/body = ~20us/CU > 15.5us VALU
// floor). Here each operand uses a different pipe:
//   e  -> LDS, but only 8 conflict-free b32 per group (64/wave total)
//   G  -> scalar pipe: per-group batch of 8 uniform dwordx8 loads, ONE wait
//         before the 8 register-only k-bodies (fixes R14's per-body stall)
//   Vw -> scalar K$.

#define BHX 16
#define SEQ 512
#define DDIM 64

typedef float f4 __attribute__((ext_vector_type(4)));

// Both projections in one launch. blocks 0..255: query->eq, 256..511: keys->gk.
// (R12-proven, no pins.)
__global__ __launch_bounds__(256) void proj_kernel(
    const float* __restrict__ query, const float* __restrict__ keys,
    const float* __restrict__ Wa_w,  const float* __restrict__ Wa_b,
    const float* __restrict__ Ua_w,  const float* __restrict__ Ua_b,
    float* __restrict__ eq, float* __restrict__ gk)
{
  const int t = threadIdx.x, lane = t & 63, wave = t >> 6;
  const bool is_k = blockIdx.x >= 256;
  const float* __restrict__ X  = is_k ? keys : query;
  const float* __restrict__ W  = is_k ? Ua_w : Wa_w;
  const float* __restrict__ Bv = is_k ? Ua_b : Wa_b;
  float* __restrict__ out      = is_k ? gk : eq;
  const int row0 = (blockIdx.x & 255) * 32;

  float w[64];
  const float4* W4 = (const float4*)(W + lane * DDIM);
#pragma unroll
  for (int i = 0; i < 16; ++i) {
    float4 v = W4[i];
    w[4*i] = v.x; w[4*i+1] = v.y; w[4*i+2] = v.z; w[4*i+3] = v.w;
  }

  const float C = 2.885390081777926815f;          // 2*log2(e)
  const float b = Bv[lane];

#pragma unroll 1
  for (int i = 0; i < 8; ++i) {
    const int r   = row0 + wave * 8 + i;
    const int off = __builtin_amdgcn_readfirstlane(r * DDIM);
    const float* xr = X + off;                    // wave-uniform -> s_load
    float a0 = 0, a1 = 0, a2 = 0, a3 = 0;
#pragma unroll
    for (int e = 0; e < 64; e += 4) {
      a0 = __builtin_fmaf(xr[e],     w[e],     a0);
      a1 = __builtin_fmaf(xr[e + 1], w[e + 1], a1);
      a2 = __builtin_fmaf(xr[e + 2], w[e + 2], a2);
      a3 = __builtin_fmaf(xr[e + 3], w[e + 3], a3);
    }
    float p = ((a0 + a1) + (a2 + a3)) + b;
    out[(size_t)r * DDIM + lane] = __builtin_amdgcn_exp2f(C * p);
  }
}

// Grid (16,8,16)=2048 blocks. Block tile: 64 q x 32 k.
// Wave w: k in [8w, 8w+8), lane = q. LDS 16.6KB (eql, reused for out-staging).
__global__ __launch_bounds__(256, 4) void score_kernel(
    const float* __restrict__ eq,   // [BH*512][64]
    const float* __restrict__ gk,   // [BH*512][64]
    const float* __restrict__ Vw,   // [64]
    const float* __restrict__ Vb,   // [1]
    float* __restrict__ out)        // [BH,512,512]
{
  __shared__ float eql[DDIM][65];   // [d][q] transposed, +1 pad (16.6 KB)

  const int bh   = blockIdx.z;
  const int q0   = blockIdx.y * 64;
  const int k0   = blockIdx.x * 32;
  const int t    = threadIdx.x;
  const int lane = t & 63;          // = q within tile
  const int wave = t >> 6;          // k-strip

  // ---- stage eq tile TRANSPOSED: [d][q] ----
  {
    const float* eqb = eq + (size_t)(bh * SEQ + q0) * DDIM;
#pragma unroll
    for (int h = 0; h < 4; ++h) {
      const int idx = t + 256 * h;        // 0..1023 quads
      const int q   = idx >> 4;
      const int d0  = (idx & 15) * 4;
      const f4 v = *(const f4*)(eqb + q * DDIM + d0);
      eql[d0][q]     = v.x;
      eql[d0 + 1][q] = v.y;
      eql[d0 + 2][q] = v.z;
      eql[d0 + 3][q] = v.w;
    }
  }

  // acc0 = V_b + sum_d V_w[d]  (uniform scalar)
  float acc0 = Vb[0];
#pragma unroll
  for (int d = 0; d < 64; ++d) acc0 += Vw[d];

  __syncthreads();

  float acc[8] = {0.f, 0.f, 0.f, 0.f, 0.f, 0.f, 0.f, 0.f};
  // wave-uniform G base for this wave's 8 k rows (readfirstlane -> scalar)
  const int goff = __builtin_amdgcn_readfirstlane(
      (bh * SEQ + k0) * DDIM + (threadIdx.x >> 6) * 8 * DDIM);
  const float* Gb = gk + goff;

#pragma unroll 1
  for (int g = 0; g < 8; ++g) {           // d-groups of 8
    // lane's 8 e-values (its q-row): conflict-free b32, reused across 8 k.
    float e_[8];
#pragma unroll
    for (int j = 0; j < 8; ++j) e_[j] = eql[8 * g + j][lane];
    float vw[8];
#pragma unroll
    for (int j = 0; j < 8; ++j) vw[j] = Vw[8 * g + j];

    // ---- batched G prefetch: ALL 64 floats for this group, then one wait.
    // Uniform base + affine offsets -> 8 contiguous s_load_dwordx8.
    float Gc[64];
#pragma unroll
    for (int kk = 0; kk < 8; ++kk)
#pragma unroll
      for (int j = 0; j < 8; ++j)
        Gc[kk * 8 + j] = Gb[kk * DDIM + 8 * g + j];

#pragma unroll
    for (int kk = 0; kk < 8; ++kk) {      // register-only bodies; acc static
      float A[8];
#pragma unroll
      for (int j = 0; j < 8; ++j)
        A[j] = __builtin_fmaf(e_[j], Gc[kk * 8 + j], 1.0f);
      // tree8: sum_j vw[j]/A[j] = num/P, 1 rcp
      const float n01 = __builtin_fmaf(vw[1], A[0], vw[0] * A[1]);
      const float n23 = __builtin_fmaf(vw[3], A[2], vw[2] * A[3]);
      const float n45 = __builtin_fmaf(vw[5], A[4], vw[4] * A[5]);
      const float n67 = __builtin_fmaf(vw[7], A[6], vw[6] * A[7]);
      const float P01 = A[0] * A[1], P23 = A[2] * A[3];
      const float P45 = A[4] * A[5], P67 = A[6] * A[7];
      const float n0123 = __builtin_fmaf(n23, P01, n01 * P23);
      const float n4567 = __builtin_fmaf(n67, P45, n45 * P67);
      const float P0123 = P01 * P23, P4567 = P45 * P67;
      const float num = __builtin_fmaf(n4567, P0123, n0123 * P4567);
      const float P   = P0123 * P4567;    // product of 8 A's >= 1: safe
      acc[kk] = __builtin_fmaf(num, __builtin_amdgcn_rcpf(P), acc[kk]);
    }
  }

  // ---- transpose results through (reused) LDS for coalesced stores ----
  __syncthreads();                        // all eql reads complete
  float* lo = &eql[0][0];                 // reuse as [64 q][33 k]
#pragma unroll
  for (int kk = 0; kk < 8; ++kk)          // bank (q + k)%32 -> 2/bank
    lo[lane * 33 + wave * 8 + kk] = __builtin_fmaf(-2.f, acc[kk], acc0);
  __syncthreads();

  {
    const int row = t >> 2;               // q row 0..63
    const int c0  = (t & 3) * 8;          // k col start
    const float* src = lo + row * 33 + c0;
    f4 v0, v1;
    v0.x = src[0]; v0.y = src[1]; v0.z = src[2]; v0.w = src[3];
    v1.x = src[4]; v1.y = src[5]; v1.z = src[6]; v1.w = src[7];
    float* dst = out + (size_t)(bh * SEQ + q0 + row) * SEQ + k0 + c0;
    *(f4*)(dst)     = v0;
    *(f4*)(dst + 4) = v1;
  }
}

extern "C" void kernel_launch(void* const* d_in, const int* in_sizes, int n_in,
                              void* d_out, int out_size, void* d_ws, size_t ws_size,
                              hipStream_t stream) {
  const float* query = (const float*)d_in[0];  // [2,8,512,64]
  const float* keys  = (const float*)d_in[1];  // [2,8,512,64]
  const float* Wa_w  = (const float*)d_in[2];  // [64,64]
  const float* Wa_b  = (const float*)d_in[3];  // [64]
  const float* Ua_w  = (const float*)d_in[4];  // [64,64]
  const float* Ua_b  = (const float*)d_in[5];  // [64]
  const float* V_w   = (const float*)d_in[6];  // [64]
  const float* V_b   = (const float*)d_in[7];  // [1]
  float* out = (float*)d_out;

  const int R = BHX * SEQ;                 // 8192 rows each side
  float* eqw = (float*)d_ws;               // 2 MiB
  float* gkw = eqw + (size_t)R * DDIM;     // 2 MiB

  proj_kernel<<<512, 256, 0, stream>>>(query, keys, Wa_w, Wa_b,
                                       Ua_w, Ua_b, eqw, gkw);

  dim3 grid(SEQ / 32, SEQ / 64, BHX);      // (16,8,16) = 2048 blocks
  score_kernel<<<grid, 256, 0, stream>>>(eqw, gkw, V_w, V_b, out);
}